// Round 2
// baseline (547.802 us; speedup 1.0000x reference)
//
#include <hip/hip_runtime.h>

// SimpleAttention: B=8, S=2048, H=256
//   Q = q@Wq * (1/sqrt(H)) ; K = k@Wk ; V = v@Wv  (bf16 in ws)
//   out = softmax(mask? -inf : Q@K^T) @ V          (fp32 out)
// R1 fix: mask is shipped as int32 (harness converts jax bool -> int), was
// read as uint8 -> saw garbage mask. Single change this round to isolate it.

#define B_ 8
#define S_ 2048
#define H_ 256

typedef __attribute__((ext_vector_type(8))) short s16x8;   // 8 bf16 (4 VGPRs) MFMA A/B frag
typedef __attribute__((ext_vector_type(4))) float f32x4;   // MFMA C/D frag
typedef __attribute__((ext_vector_type(4))) unsigned short u16x4;

#if __has_builtin(__builtin_amdgcn_exp2f)
#define EXP2F(x) __builtin_amdgcn_exp2f(x)
#else
#define EXP2F(x) exp2f(x)
#endif
#define L2E 1.4426950408889634f

__device__ __forceinline__ unsigned short f2bf(float f) {
  unsigned int u = __builtin_bit_cast(unsigned int, f);
  u += 0x7fffu + ((u >> 16) & 1u);   // RNE
  return (unsigned short)(u >> 16);
}

__device__ __forceinline__ f32x4 mfma_bf16(s16x8 a, s16x8 b, f32x4 c) {
  return __builtin_amdgcn_mfma_f32_16x16x32_bf16(a, b, c, 0, 0, 0);
}

// select v[r] for runtime r in 0..3 (branchless)
__device__ __forceinline__ float sel4(const float v[4], int r) {
  float t0 = (r & 1) ? v[1] : v[0];
  float t1 = (r & 1) ? v[3] : v[2];
  return (r & 2) ? t1 : t0;
}

// ---------------------------------------------------------------------------
// Kernel 0: W[h][n] fp32 -> Wt[n][h] bf16, for the 3 projection weights.
// ---------------------------------------------------------------------------
__global__ __launch_bounds__(256) void wt_kernel(const float* __restrict__ Wq,
                                                 const float* __restrict__ Wk,
                                                 const float* __restrict__ Wv,
                                                 unsigned short* __restrict__ Wt) {
  int z = blockIdx.y;
  const float* W = (z == 0) ? Wq : (z == 1) ? Wk : Wv;
  unsigned short* dst = Wt + z * 65536;
  int idx = blockIdx.x * 256 + threadIdx.x;   // 0..65535
  int n = idx >> 8, h = idx & 255;
  dst[n * 256 + h] = f2bf(W[h * 256 + n]);
}

// ---------------------------------------------------------------------------
// Kernel 1: projections. Block = 64 rows x all 256 cols, 4 waves.
// grid (256, 3): x = row tile (M=B*S=16384), y = which projection.
//   z=0: Q = q@Wq (scaled 1/16), row-major bf16
//   z=1: K = k@Wk, row-major bf16
//   z=2: V = v@Wv, stored transposed per batch: Vt[b][d][s]
// ---------------------------------------------------------------------------
__global__ __launch_bounds__(256) void proj_kernel(
    const float* __restrict__ Xq, const float* __restrict__ Xk, const float* __restrict__ Xv,
    const unsigned short* __restrict__ Wt,
    unsigned short* __restrict__ Qb, unsigned short* __restrict__ Kb,
    unsigned short* __restrict__ Vt) {
  __shared__ unsigned short Xs[64 * 32];    // 4KB, row = 32 elts = 4 x 16B chunks
  __shared__ unsigned short Ws[256 * 32];   // 16KB

  int z = blockIdx.y;
  const float* X = (z == 0) ? Xq : (z == 1) ? Xk : Xv;
  const unsigned short* Wz = Wt + z * 65536;

  int t = threadIdx.x;
  int w = t >> 6, lane = t & 63, quad = lane >> 4, l15 = lane & 15;
  int m0 = blockIdx.x * 64;

  f32x4 zero4 = {0.f, 0.f, 0.f, 0.f};
  f32x4 acc[16];
#pragma unroll
  for (int i = 0; i < 16; ++i) acc[i] = zero4;

  for (int c8 = 0; c8 < 8; ++c8) {
    // stage X chunk: fp32 -> bf16, swizzled chunk position (p ^ ((m>>1)&3))
    {
      int m = t >> 2, p = t & 3;
      const float* src = X + (size_t)(m0 + m) * H_ + c8 * 32 + p * 8;
      float4 f0 = *(const float4*)(src);
      float4 f1 = *(const float4*)(src + 4);
      s16x8 hv;
      hv[0] = (short)f2bf(f0.x); hv[1] = (short)f2bf(f0.y);
      hv[2] = (short)f2bf(f0.z); hv[3] = (short)f2bf(f0.w);
      hv[4] = (short)f2bf(f1.x); hv[5] = (short)f2bf(f1.y);
      hv[6] = (short)f2bf(f1.z); hv[7] = (short)f2bf(f1.w);
      *(s16x8*)&Xs[m * 32 + ((p ^ ((m >> 1) & 3)) << 3)] = hv;
    }
    // stage W^T chunk: LDS pos p holds global chunk p^s(n)
#pragma unroll
    for (int i = 0; i < 4; ++i) {
      int c = i * 256 + t;
      int n = c >> 2, p = c & 3;
      const unsigned short* src = Wz + n * 256 + c8 * 32 + ((p ^ ((n >> 1) & 3)) << 3);
      uint4 dv = *(const uint4*)src;
      *(uint4*)&Ws[n * 32 + (p << 3)] = dv;
    }
    __syncthreads();

    int mloc = w * 16 + l15;
    s16x8 af = *(const s16x8*)&Xs[mloc * 32 + ((quad ^ ((mloc >> 1) & 3)) << 3)];
#pragma unroll
    for (int nf = 0; nf < 16; ++nf) {
      int n = nf * 16 + l15;
      s16x8 bf = *(const s16x8*)&Ws[n * 32 + ((quad ^ ((n >> 1) & 3)) << 3)];
      acc[nf] = mfma_bf16(af, bf, acc[nf]);
    }
    __syncthreads();
  }

  // epilogue. C layout: col = lane&15 (+16*nf), row = quad*4 + reg
  if (z < 2) {
    unsigned short* Y = (z == 0) ? Qb : Kb;
    float scale = (z == 0) ? 0.0625f : 1.0f;   // fold 1/sqrt(H) into Q
#pragma unroll
    for (int nf = 0; nf < 16; ++nf) {
      int n = nf * 16 + l15;
#pragma unroll
      for (int r = 0; r < 4; ++r) {
        int m = m0 + w * 16 + quad * 4 + r;
        Y[(size_t)m * H_ + n] = f2bf(acc[nf][r] * scale);
      }
    }
  } else {
    // Vt[b][d][s]: 4 consecutive s (regs) -> 8B store
    int mg = m0 + w * 16 + quad * 4;          // global row (= b*2048 + s)
    int b = mg >> 11, s = mg & 2047;
#pragma unroll
    for (int nf = 0; nf < 16; ++nf) {
      int d = nf * 16 + l15;
      u16x4 pk;
      pk[0] = f2bf(acc[nf][0]); pk[1] = f2bf(acc[nf][1]);
      pk[2] = f2bf(acc[nf][2]); pk[3] = f2bf(acc[nf][3]);
      *(u16x4*)&Vt[(size_t)b * (H_ * S_) + (size_t)d * S_ + s] = pk;
    }
  }
}

// ---------------------------------------------------------------------------
// Kernel 2: flash attention. grid (S/64=32, B=8), 256 threads (4 waves).
// Wave w owns q rows [q0+w*16, +16). Q lives in registers (8 A-frags).
// LDS: Ks [64 key][256 d] 32KB | Vs [256 d][64 key] 32KB; P (8KB) reuses Ks
// after a barrier. All tiles XOR-swizzled at 16B-chunk granularity.
// PV computed as O^T = V^T x P^T -> coalesced float4 epilogue stores.
// ---------------------------------------------------------------------------
__global__ __launch_bounds__(256) void attn_kernel(
    const unsigned short* __restrict__ Qb, const unsigned short* __restrict__ Kb,
    const unsigned short* __restrict__ Vt, const int* __restrict__ mask,
    float* __restrict__ out) {
  __shared__ unsigned short lds[32768];   // 64KB
  unsigned short* Ks = lds;               // [64][256]
  unsigned short* Vs = lds + 16384;       // [256][64]
  unsigned short* Ps = lds;               // [wave][16][64], overlaps Ks

  int t = threadIdx.x;
  int w = t >> 6, lane = t & 63, quad = lane >> 4, l15 = lane & 15;
  int q0 = blockIdx.x * 64;
  int b = blockIdx.y;

  // Q A-frags: lane holds Q[q0+w*16+l15][quad*8 + 32c .. +7]
  s16x8 qa[8];
  {
    const unsigned short* qp =
        Qb + ((size_t)b * S_ + q0 + w * 16 + l15) * H_ + quad * 8;
#pragma unroll
    for (int c = 0; c < 8; ++c) qa[c] = *(const s16x8*)(qp + 32 * c);
  }

  f32x4 zero4 = {0.f, 0.f, 0.f, 0.f};
  f32x4 acc[16];                                   // O^T: rows d (16 mf), cols q
#pragma unroll
  for (int i = 0; i < 16; ++i) acc[i] = zero4;
  float m_r[4], l_r[4];
#pragma unroll
  for (int r = 0; r < 4; ++r) { m_r[r] = -1e30f; l_r[r] = 0.f; }

  const int* mbase =
      mask + (size_t)b * S_ * S_ + (size_t)(q0 + w * 16 + quad * 4) * S_ + l15;

  for (int kt = 0; kt < 32; ++kt) {
    int k0 = kt * 64;
    __syncthreads();   // previous iter done reading Ks/Vs/Ps
    // ---- stage K tile [64 key][256 d], swizzle chunk p -> p^(key&7)
    {
      const unsigned short* kg = Kb + ((size_t)b * S_ + k0) * H_;
#pragma unroll
      for (int i = 0; i < 8; ++i) {
        int c = i * 256 + t;
        int key = c >> 5, p = c & 31;
        uint4 dv = *(const uint4*)(kg + key * H_ + ((p ^ (key & 7)) << 3));
        *(uint4*)&Ks[key * 256 + (p << 3)] = dv;
      }
      const unsigned short* vg = Vt + (size_t)b * (H_ * S_) + k0;
#pragma unroll
      for (int i = 0; i < 8; ++i) {
        int c = i * 256 + t;
        int d = c >> 3, p = c & 7;
        uint4 dv = *(const uint4*)(vg + (size_t)d * S_ + ((p ^ (d & 7)) << 3));
        *(uint4*)&Vs[d * 64 + (p << 3)] = dv;
      }
    }
    __syncthreads();

    // ---- S = Q K^T : C rows = q (quad*4+reg), cols = key (l15 + 16nf)
    f32x4 sacc[4];
#pragma unroll
    for (int nf = 0; nf < 4; ++nf) sacc[nf] = zero4;
#pragma unroll
    for (int c = 0; c < 8; ++c) {
#pragma unroll
      for (int nf = 0; nf < 4; ++nf) {
        int n = nf * 16 + l15;
        s16x8 kb = *(const s16x8*)&Ks[n * 256 + (((quad + 4 * c) ^ (n & 7)) << 3)];
        sacc[nf] = mfma_bf16(qa[c], kb, sacc[nf]);
      }
    }

    // ---- mask + online softmax (fp32). row q = quad*4 + r across 16 cols.
    float sv[4][4], mt[4];
#pragma unroll
    for (int r = 0; r < 4; ++r) mt[r] = -1e30f;
    const int* mrow = mbase + k0;
#pragma unroll
    for (int nf = 0; nf < 4; ++nf) {
#pragma unroll
      for (int r = 0; r < 4; ++r) {
        float s = sacc[nf][r];
        if (mrow[(size_t)r * S_ + nf * 16]) s = -1e30f;
        sv[nf][r] = s;
        mt[r] = fmaxf(mt[r], s);
      }
    }
#pragma unroll
    for (int r = 0; r < 4; ++r) {
      float m = mt[r];
#pragma unroll
      for (int d = 1; d < 16; d <<= 1) m = fmaxf(m, __shfl_xor(m, d, 64));
      mt[r] = m;
    }
    float alpha[4], pvv[4][4];
#pragma unroll
    for (int r = 0; r < 4; ++r) {
      float mn = fmaxf(m_r[r], mt[r]);
      alpha[r] = EXP2F((m_r[r] - mn) * L2E);
      m_r[r] = mn;
      float rs = 0.f;
#pragma unroll
      for (int nf = 0; nf < 4; ++nf) {
        float p = EXP2F((sv[nf][r] - mn) * L2E);
        pvv[nf][r] = p;
        rs += p;
      }
#pragma unroll
      for (int d = 1; d < 16; d <<= 1) rs += __shfl_xor(rs, d, 64);
      l_r[r] = l_r[r] * alpha[r] + rs;
    }

    __syncthreads();   // all waves done reading Ks before P overwrites it

    // ---- write P (bf16) to LDS, wave-private [16 q][64 key], swizzled
#pragma unroll
    for (int nf = 0; nf < 4; ++nf) {
#pragma unroll
      for (int r = 0; r < 4; ++r) {
        int key = nf * 16 + l15;
        int ql = quad * 4 + r;
        int idx = w * 1024 + ql * 64 + ((((key >> 3)) ^ (ql & 7)) << 3) + (key & 7);
        Ps[idx] = f2bf(pvv[nf][r]);
      }
    }
    // ---- rescale O^T by alpha of its column q = l15 (cross-lane fetch)
    {
      float a4[4];
      int srcl = (l15 >> 2) << 4;
#pragma unroll
      for (int r = 0; r < 4; ++r) a4[r] = __shfl(alpha[r], srcl, 64);
      float aq = sel4(a4, l15 & 3);
#pragma unroll
      for (int mf = 0; mf < 16; ++mf) {
        acc[mf][0] *= aq; acc[mf][1] *= aq; acc[mf][2] *= aq; acc[mf][3] *= aq;
      }
    }
    __syncthreads();

    // ---- O^T += V^T P^T : A = Vs frag (m=d), B = Ps frag (n=q)
#pragma unroll
    for (int kc = 0; kc < 2; ++kc) {
      int g = quad + 4 * kc;
      s16x8 bp = *(const s16x8*)&Ps[w * 1024 + l15 * 64 + ((g ^ (l15 & 7)) << 3)];
#pragma unroll
      for (int mf = 0; mf < 16; ++mf) {
        int d = mf * 16 + l15;
        s16x8 av = *(const s16x8*)&Vs[d * 64 + ((g ^ (d & 7)) << 3)];
        acc[mf] = mfma_bf16(av, bp, acc[mf]);
      }
    }
  }

  // ---- epilogue: O = O^T / l, coalesced float4 stores
  float l4[4];
  int srcl = (l15 >> 2) << 4;
#pragma unroll
  for (int r = 0; r < 4; ++r) l4[r] = __shfl(l_r[r], srcl, 64);
  float lq = sel4(l4, l15 & 3);
  float linv = (lq > 0.f) ? (1.0f / lq) : 0.f;   // fully-masked row -> zeros

  float* op = out + ((size_t)b * S_ + q0 + w * 16 + l15) * H_ + quad * 4;
#pragma unroll
  for (int mf = 0; mf < 16; ++mf) {
    float4 o;
    o.x = acc[mf][0] * linv; o.y = acc[mf][1] * linv;
    o.z = acc[mf][2] * linv; o.w = acc[mf][3] * linv;
    *(float4*)(op + mf * 16) = o;
  }
}

// ---------------------------------------------------------------------------
extern "C" void kernel_launch(void* const* d_in, const int* in_sizes, int n_in,
                              void* d_out, int out_size, void* d_ws, size_t ws_size,
                              hipStream_t stream) {
  const float* k_in = (const float*)d_in[0];
  const float* q_in = (const float*)d_in[1];
  const float* v_in = (const float*)d_in[2];
  const int* mask = (const int*)d_in[3];   // harness ships bool as int32
  const float* Wq = (const float*)d_in[4];
  const float* Wk = (const float*)d_in[5];
  const float* Wv = (const float*)d_in[6];
  float* out = (float*)d_out;

  // workspace: Qb | Kb | Vt (bf16, 8MB each) | Wt (384KB) = ~24.4MB
  unsigned short* Qb = (unsigned short*)d_ws;
  unsigned short* Kb = Qb + (size_t)4194304;
  unsigned short* Vt = Kb + (size_t)4194304;
  unsigned short* Wt = Vt + (size_t)4194304;

  hipLaunchKernelGGL(wt_kernel, dim3(256, 3), dim3(256), 0, stream, Wq, Wk, Wv, Wt);
  hipLaunchKernelGGL(proj_kernel, dim3(256, 3), dim3(256), 0, stream,
                     q_in, k_in, v_in, Wt, Qb, Kb, Vt);
  hipLaunchKernelGGL(attn_kernel, dim3(32, 8), dim3(256), 0, stream,
                     Qb, Kb, Vt, mask, out);
}

// Round 3
// 539.278 us; speedup vs baseline: 1.0158x; 1.0158x over previous
//
#include <hip/hip_runtime.h>

// SimpleAttention: B=8, S=2048, H=256
// R3: K-split x3 flash attention (768 blocks = 3/CU), BK=32, 36KB LDS,
//     2 barriers/iter, reg-double-buffered K/V staging, coalesced V path
//     (proj row-major + vtrans), tiled wt transpose, combine kernel.

#define B_ 8
#define S_ 2048
#define H_ 256

typedef __attribute__((ext_vector_type(8))) short s16x8;   // 8 bf16 MFMA A/B frag
typedef __attribute__((ext_vector_type(4))) float f32x4;   // MFMA C/D frag
typedef __attribute__((ext_vector_type(4))) unsigned short u16x4;
typedef __attribute__((ext_vector_type(8))) unsigned short u16x8;

#if __has_builtin(__builtin_amdgcn_exp2f)
#define EXP2F(x) __builtin_amdgcn_exp2f(x)
#else
#define EXP2F(x) exp2f(x)
#endif
#define L2E 1.4426950408889634f

__device__ __forceinline__ unsigned short f2bf(float f) {
  unsigned int u = __builtin_bit_cast(unsigned int, f);
  u += 0x7fffu + ((u >> 16) & 1u);   // RNE
  return (unsigned short)(u >> 16);
}
__device__ __forceinline__ float bf2f(unsigned short h) {
  unsigned int u = ((unsigned int)h) << 16;
  return __builtin_bit_cast(float, u);
}
__device__ __forceinline__ f32x4 mfma_bf16(s16x8 a, s16x8 b, f32x4 c) {
  return __builtin_amdgcn_mfma_f32_16x16x32_bf16(a, b, c, 0, 0, 0);
}
__device__ __forceinline__ float sel4(const float v[4], int r) {
  float t0 = (r & 1) ? v[1] : v[0];
  float t1 = (r & 1) ? v[3] : v[2];
  return (r & 2) ? t1 : t0;
}

// ---------------------------------------------------------------------------
// Kernel 0: W[h][n] fp32 -> Wt[n][h] bf16, LDS-tiled transpose (coalesced both
// sides). grid (16, 3): 4x4 tiles of 64x64.
// ---------------------------------------------------------------------------
__global__ __launch_bounds__(256) void wt_kernel(const float* __restrict__ Wq,
                                                 const float* __restrict__ Wk,
                                                 const float* __restrict__ Wv,
                                                 unsigned short* __restrict__ Wt) {
  __shared__ unsigned short tile[64 * 72];   // [h][n], stride 72 breaks banks
  int z = blockIdx.y;
  const float* W = (z == 0) ? Wq : (z == 1) ? Wk : Wv;
  int n0 = (blockIdx.x & 3) * 64, h0 = (blockIdx.x >> 2) * 64;
  int t = threadIdx.x;
#pragma unroll
  for (int j = 0; j < 4; ++j) {
    int c = j * 256 + t;              // 0..1023
    int i = c >> 4, ch = c & 15;      // h row, 4-float chunk
    float4 f = *(const float4*)&W[(h0 + i) * 256 + n0 + ch * 4];
    u16x4 p;
    p[0] = f2bf(f.x); p[1] = f2bf(f.y); p[2] = f2bf(f.z); p[3] = f2bf(f.w);
    *(u16x4*)&tile[i * 72 + ch * 4] = p;
  }
  __syncthreads();
#pragma unroll
  for (int j = 0; j < 2; ++j) {
    int c = j * 256 + t;              // 0..511
    int nr = c >> 3, ch = c & 7;      // n row, 8-h chunk
    u16x8 o;
#pragma unroll
    for (int k = 0; k < 8; ++k) o[k] = tile[(ch * 8 + k) * 72 + nr];
    *(u16x8*)&Wt[z * 65536 + (n0 + nr) * 256 + h0 + ch * 8] = o;
  }
}

// ---------------------------------------------------------------------------
// Kernel 1: projections. Block = 64 rows x 256 cols, 4 waves. grid (256,3).
//   z=0: Q*1/16 -> Qb ; z=1: K -> Kb ; z=2: V -> Vr (ALL row-major bf16 now).
// ---------------------------------------------------------------------------
__global__ __launch_bounds__(256) void proj_kernel(
    const float* __restrict__ Xq, const float* __restrict__ Xk, const float* __restrict__ Xv,
    const unsigned short* __restrict__ Wt,
    unsigned short* __restrict__ Qb, unsigned short* __restrict__ Kb,
    unsigned short* __restrict__ Vr) {
  __shared__ unsigned short Xs[64 * 32];    // 4KB
  __shared__ unsigned short Ws[256 * 32];   // 16KB

  int z = blockIdx.y;
  const float* X = (z == 0) ? Xq : (z == 1) ? Xk : Xv;
  const unsigned short* Wz = Wt + z * 65536;

  int t = threadIdx.x;
  int w = t >> 6, lane = t & 63, quad = lane >> 4, l15 = lane & 15;
  int m0 = blockIdx.x * 64;

  f32x4 zero4 = {0.f, 0.f, 0.f, 0.f};
  f32x4 acc[16];
#pragma unroll
  for (int i = 0; i < 16; ++i) acc[i] = zero4;

  for (int c8 = 0; c8 < 8; ++c8) {
    {
      int m = t >> 2, p = t & 3;
      const float* src = X + (size_t)(m0 + m) * H_ + c8 * 32 + p * 8;
      float4 f0 = *(const float4*)(src);
      float4 f1 = *(const float4*)(src + 4);
      s16x8 hv;
      hv[0] = (short)f2bf(f0.x); hv[1] = (short)f2bf(f0.y);
      hv[2] = (short)f2bf(f0.z); hv[3] = (short)f2bf(f0.w);
      hv[4] = (short)f2bf(f1.x); hv[5] = (short)f2bf(f1.y);
      hv[6] = (short)f2bf(f1.z); hv[7] = (short)f2bf(f1.w);
      *(s16x8*)&Xs[m * 32 + ((p ^ ((m >> 1) & 3)) << 3)] = hv;
    }
#pragma unroll
    for (int i = 0; i < 4; ++i) {
      int c = i * 256 + t;
      int n = c >> 2, p = c & 3;
      const unsigned short* src = Wz + n * 256 + c8 * 32 + ((p ^ ((n >> 1) & 3)) << 3);
      uint4 dv = *(const uint4*)src;
      *(uint4*)&Ws[n * 32 + (p << 3)] = dv;
    }
    __syncthreads();

    int mloc = w * 16 + l15;
    s16x8 af = *(const s16x8*)&Xs[mloc * 32 + ((quad ^ ((mloc >> 1) & 3)) << 3)];
#pragma unroll
    for (int nf = 0; nf < 16; ++nf) {
      int n = nf * 16 + l15;
      s16x8 bf = *(const s16x8*)&Ws[n * 32 + ((quad ^ ((n >> 1) & 3)) << 3)];
      acc[nf] = mfma_bf16(af, bf, acc[nf]);
    }
    __syncthreads();
  }

  unsigned short* Y = (z == 0) ? Qb : (z == 1) ? Kb : Vr;
  float scale = (z == 0) ? 0.0625f : 1.0f;
#pragma unroll
  for (int nf = 0; nf < 16; ++nf) {
    int n = nf * 16 + l15;
#pragma unroll
    for (int r = 0; r < 4; ++r) {
      int m = m0 + w * 16 + quad * 4 + r;
      Y[(size_t)m * H_ + n] = f2bf(acc[nf][r] * scale);
    }
  }
}

// ---------------------------------------------------------------------------
// Kernel 2: Vr[b][s][d] -> Vt[b][d][s], 64x64 LDS tiles. grid (128, 8).
// ---------------------------------------------------------------------------
__global__ __launch_bounds__(256) void vtrans_kernel(
    const unsigned short* __restrict__ Vr, unsigned short* __restrict__ Vt) {
  __shared__ unsigned short tile[64 * 72];
  int s0 = (blockIdx.x & 31) * 64;
  int d0 = (blockIdx.x >> 5) * 64;
  int b = blockIdx.y;
  int t = threadIdx.x;
#pragma unroll
  for (int j = 0; j < 2; ++j) {
    int c = j * 256 + t;              // 0..511
    int i = c >> 3, ch = c & 7;       // s row, 8-d chunk
    u16x8 v = *(const u16x8*)&Vr[((size_t)b * S_ + s0 + i) * H_ + d0 + ch * 8];
    *(u16x8*)&tile[i * 72 + ch * 8] = v;
  }
  __syncthreads();
#pragma unroll
  for (int j = 0; j < 2; ++j) {
    int c = j * 256 + t;
    int dr = c >> 3, ch = c & 7;      // d row, 8-s chunk
    u16x8 o;
#pragma unroll
    for (int k = 0; k < 8; ++k) o[k] = tile[(ch * 8 + k) * 72 + dr];
    *(u16x8*)&Vt[((size_t)b * H_ + d0 + dr) * S_ + s0 + ch * 8] = o;
  }
}

// ---------------------------------------------------------------------------
// Kernel 3: flash attention, K-split partials. grid (32, 8, nsplit), 4 waves.
// BK=32. LDS: Ks[32][256] 16KB | Vs[256][32] 16KB | Ps[4][16][32] 4KB = 36KB.
// Reg-double-buffered staging: global loads for tile kt+1 issued after syncB.
// nsplit==1: writes out directly; else unnormalized O^T (bf16) + (m,l) to ws.
// ---------------------------------------------------------------------------
__global__ __launch_bounds__(256, 3) void attn_kernel(
    const unsigned short* __restrict__ Qb, const unsigned short* __restrict__ Kb,
    const unsigned short* __restrict__ Vt, const int* __restrict__ mask,
    unsigned short* __restrict__ Op, float* __restrict__ Ml,
    float* __restrict__ out) {
  __shared__ unsigned short lds[18432];
  unsigned short* Ks = lds;            // [32 key][256 d]
  unsigned short* Vs = lds + 8192;     // [256 d][32 key]
  unsigned short* Ps = lds + 16384;    // [wave][16 q][32 key]

  int t = threadIdx.x;
  int w = t >> 6, lane = t & 63, quad = lane >> 4, l15 = lane & 15;
  int q0 = blockIdx.x * 64;
  int b = blockIdx.y;
  int split = blockIdx.z, nsplit = gridDim.z;
  int kbeg = (64 * split) / nsplit, kend = (64 * (split + 1)) / nsplit;

  // Q A-frags
  s16x8 qa[8];
  {
    const unsigned short* qp =
        Qb + ((size_t)b * S_ + q0 + w * 16 + l15) * H_ + quad * 8;
#pragma unroll
    for (int c = 0; c < 8; ++c) qa[c] = *(const s16x8*)(qp + 32 * c);
  }

  // staging address precompute (per-thread constants)
  int ksoff[4], vsoff[4];
  size_t kgoff[4], vgoff[4];
#pragma unroll
  for (int i = 0; i < 4; ++i) {
    int c = i * 256 + t;
    int key = c >> 5, p = c & 31;          // K: 32 rows x 32 chunks
    ksoff[i] = key * 256 + (p << 3);
    kgoff[i] = ((size_t)b * S_ + key) * H_ + ((p ^ (key & 7)) << 3);
    int d = c >> 2, pv = c & 3;            // V: 256 rows x 4 chunks
    vsoff[i] = d * 32 + (pv << 3);
    vgoff[i] = ((size_t)b * H_ + d) * S_ + ((pv ^ (d & 3)) << 3);
  }

  f32x4 zero4 = {0.f, 0.f, 0.f, 0.f};
  f32x4 acc[16];
#pragma unroll
  for (int i = 0; i < 16; ++i) acc[i] = zero4;
  float m_r[4], l_r[4];
#pragma unroll
  for (int r = 0; r < 4; ++r) { m_r[r] = -1e30f; l_r[r] = 0.f; }

  const int* mbase =
      mask + ((size_t)b * S_ + q0 + w * 16 + quad * 4) * S_ + l15;

  // preload first tiles into regs
  uint4 kreg[4], vreg[4];
  {
    size_t k0h = (size_t)kbeg * 32 * H_;
    int k0e = kbeg * 32;
#pragma unroll
    for (int i = 0; i < 4; ++i) {
      kreg[i] = *(const uint4*)(Kb + kgoff[i] + k0h);
      vreg[i] = *(const uint4*)(Vt + vgoff[i] + k0e);
    }
  }

  for (int kt = kbeg; kt < kend; ++kt) {
    int k0 = kt * 32;
    __syncthreads();   // A: previous tiles consumed
#pragma unroll
    for (int i = 0; i < 4; ++i) {
      *(uint4*)&Ks[ksoff[i]] = kreg[i];
      *(uint4*)&Vs[vsoff[i]] = vreg[i];
    }
    __syncthreads();   // B: tiles visible

    // prefetch next tiles (overlaps compute below)
    {
      int ktn = (kt + 1 < kend) ? kt + 1 : kt;
      size_t k0h = (size_t)ktn * 32 * H_;
      int k0e = ktn * 32;
#pragma unroll
      for (int i = 0; i < 4; ++i) {
        kreg[i] = *(const uint4*)(Kb + kgoff[i] + k0h);
        vreg[i] = *(const uint4*)(Vt + vgoff[i] + k0e);
      }
    }
    // mask loads for this tile (latency hidden under QK MFMAs)
    int mv[2][4];
    {
      const int* mrow = mbase + k0;
#pragma unroll
      for (int nf = 0; nf < 2; ++nf)
#pragma unroll
        for (int r = 0; r < 4; ++r)
          mv[nf][r] = mrow[(size_t)r * S_ + nf * 16];
    }

    // S = Q K^T
    f32x4 sacc[2];
#pragma unroll
    for (int nf = 0; nf < 2; ++nf) sacc[nf] = zero4;
#pragma unroll
    for (int c = 0; c < 8; ++c) {
#pragma unroll
      for (int nf = 0; nf < 2; ++nf) {
        int n = nf * 16 + l15;
        s16x8 kb = *(const s16x8*)&Ks[n * 256 + (((quad + 4 * c) ^ (n & 7)) << 3)];
        sacc[nf] = mfma_bf16(qa[c], kb, sacc[nf]);
      }
    }

    // mask + online softmax
    float pv2[2][4], mt[4];
#pragma unroll
    for (int r = 0; r < 4; ++r) mt[r] = -1e30f;
#pragma unroll
    for (int nf = 0; nf < 2; ++nf)
#pragma unroll
      for (int r = 0; r < 4; ++r) {
        float s = mv[nf][r] ? -1e30f : sacc[nf][r];
        pv2[nf][r] = s;
        mt[r] = fmaxf(mt[r], s);
      }
#pragma unroll
    for (int r = 0; r < 4; ++r) {
      float m = mt[r];
#pragma unroll
      for (int d = 1; d < 16; d <<= 1) m = fmaxf(m, __shfl_xor(m, d, 64));
      mt[r] = m;
    }
    float alpha[4];
#pragma unroll
    for (int r = 0; r < 4; ++r) {
      float mn = fmaxf(m_r[r], mt[r]);
      alpha[r] = EXP2F((m_r[r] - mn) * L2E);
      m_r[r] = mn;
      float rs = 0.f;
#pragma unroll
      for (int nf = 0; nf < 2; ++nf) {
        float p = EXP2F((pv2[nf][r] - mn) * L2E);
        pv2[nf][r] = p;
        rs += p;
      }
#pragma unroll
      for (int d = 1; d < 16; d <<= 1) rs += __shfl_xor(rs, d, 64);
      l_r[r] = l_r[r] * alpha[r] + rs;
    }

    // P -> LDS (wave-private, no barrier needed)
#pragma unroll
    for (int nf = 0; nf < 2; ++nf)
#pragma unroll
      for (int r = 0; r < 4; ++r) {
        int key = nf * 16 + l15;
        int ql = quad * 4 + r;
        Ps[w * 512 + ql * 32 + (((key >> 3) ^ (ql & 3)) << 3) + (key & 7)] =
            f2bf(pv2[nf][r]);
      }

    // rescale O^T columns by alpha of q = l15
    {
      float a4[4];
      int srcl = (l15 >> 2) << 4;
#pragma unroll
      for (int r = 0; r < 4; ++r) a4[r] = __shfl(alpha[r], srcl, 64);
      float aq = sel4(a4, l15 & 3);
#pragma unroll
      for (int mf = 0; mf < 16; ++mf) {
        acc[mf][0] *= aq; acc[mf][1] *= aq; acc[mf][2] *= aq; acc[mf][3] *= aq;
      }
    }

    // O^T += V^T P^T
    {
      s16x8 bp = *(const s16x8*)&Ps[w * 512 + l15 * 32 + ((quad ^ (l15 & 3)) << 3)];
#pragma unroll
      for (int mf = 0; mf < 16; ++mf) {
        int d = mf * 16 + l15;
        s16x8 av = *(const s16x8*)&Vs[d * 32 + ((quad ^ (d & 3)) << 3)];
        acc[mf] = mfma_bf16(av, bp, acc[mf]);
      }
    }
  }

  if (gridDim.z == 1) {
    // direct epilogue: divide by l, fp32 out
    float l4[4];
    int srcl = (l15 >> 2) << 4;
#pragma unroll
    for (int r = 0; r < 4; ++r) l4[r] = __shfl(l_r[r], srcl, 64);
    float lq = sel4(l4, l15 & 3);
    float linv = (lq > 0.f) ? (1.0f / lq) : 0.f;
    float* op = out + ((size_t)b * S_ + q0 + w * 16 + l15) * H_ + quad * 4;
#pragma unroll
    for (int mf = 0; mf < 16; ++mf) {
      float4 o;
      o.x = acc[mf][0] * linv; o.y = acc[mf][1] * linv;
      o.z = acc[mf][2] * linv; o.w = acc[mf][3] * linv;
      *(float4*)(op + mf * 16) = o;
    }
  } else {
    // partial epilogue: unnormalized O^T (bf16) + per-row (m,l)
    int qg = q0 + w * 16 + l15;
    unsigned short* op =
        Op + (((size_t)split * B_ + b) * S_ + qg) * H_ + quad * 4;
#pragma unroll
    for (int mf = 0; mf < 16; ++mf) {
      u16x4 pk;
      pk[0] = f2bf(acc[mf][0]); pk[1] = f2bf(acc[mf][1]);
      pk[2] = f2bf(acc[mf][2]); pk[3] = f2bf(acc[mf][3]);
      *(u16x4*)(op + mf * 16) = pk;
    }
    if (l15 == 0) {
#pragma unroll
      for (int r = 0; r < 4; ++r) {
        int qr = q0 + w * 16 + quad * 4 + r;
        float2 ml2 = make_float2(m_r[r], l_r[r]);
        *(float2*)&Ml[(((size_t)split * B_ + b) * S_ + qr) * 2] = ml2;
      }
    }
  }
}

// ---------------------------------------------------------------------------
// Kernel 4: combine K-split partials. grid (2048, 8) x 256 (one block per row).
// ---------------------------------------------------------------------------
__global__ __launch_bounds__(256) void combine_kernel(
    const unsigned short* __restrict__ Op, const float* __restrict__ Ml,
    float* __restrict__ out, int nsplit) {
  int q = blockIdx.x, b = blockIdx.y, d = threadIdx.x;
  float M = -1e30f;
  for (int i = 0; i < nsplit; ++i)
    M = fmaxf(M, Ml[(((size_t)i * B_ + b) * S_ + q) * 2]);
  float osum = 0.f, lsum = 0.f;
  for (int i = 0; i < nsplit; ++i) {
    size_t ro = ((size_t)i * B_ + b) * S_ + q;
    float mi = Ml[ro * 2], li = Ml[ro * 2 + 1];
    float wgt = EXP2F((mi - M) * L2E);
    lsum += wgt * li;
    osum += wgt * bf2f(Op[ro * H_ + d]);
  }
  float linv = (lsum > 0.f) ? (1.0f / lsum) : 0.f;
  out[((size_t)b * S_ + q) * H_ + d] = osum * linv;
}

// ---------------------------------------------------------------------------
extern "C" void kernel_launch(void* const* d_in, const int* in_sizes, int n_in,
                              void* d_out, int out_size, void* d_ws, size_t ws_size,
                              hipStream_t stream) {
  const float* k_in = (const float*)d_in[0];
  const float* q_in = (const float*)d_in[1];
  const float* v_in = (const float*)d_in[2];
  const int* mask = (const int*)d_in[3];
  const float* Wq = (const float*)d_in[4];
  const float* Wk = (const float*)d_in[5];
  const float* Wv = (const float*)d_in[6];
  float* out = (float*)d_out;

  // ws layout (ushort elements): Qb|Kb|Vr|Vt 4x4194304, Wt 196608,
  // Op 12582912 (3 splits bf16), Ml 98304 floats. ~56.8 MB total.
  unsigned short* Qb = (unsigned short*)d_ws;
  unsigned short* Kb = Qb + (size_t)4194304;
  unsigned short* Vr = Kb + (size_t)4194304;
  unsigned short* Vt = Vr + (size_t)4194304;
  unsigned short* Wt = Vt + (size_t)4194304;
  unsigned short* Op = Wt + (size_t)196608;
  float* Ml = (float*)(Op + (size_t)12582912);
  const size_t need = 59506688;
  int nsplit = (ws_size >= need) ? 3 : 1;

  hipLaunchKernelGGL(wt_kernel, dim3(16, 3), dim3(256), 0, stream, Wq, Wk, Wv, Wt);
  hipLaunchKernelGGL(proj_kernel, dim3(256, 3), dim3(256), 0, stream,
                     q_in, k_in, v_in, Wt, Qb, Kb, Vr);
  hipLaunchKernelGGL(vtrans_kernel, dim3(128, 8), dim3(256), 0, stream, Vr, Vt);
  hipLaunchKernelGGL(attn_kernel, dim3(32, 8, nsplit), dim3(256), 0, stream,
                     Qb, Kb, Vt, mask, Op, Ml, out);
  if (nsplit > 1)
    hipLaunchKernelGGL(combine_kernel, dim3(2048, 8), dim3(256), 0, stream,
                       Op, Ml, out, nsplit);
}

// Round 4
// 371.989 us; speedup vs baseline: 1.4726x; 1.4497x over previous
//
#include <hip/hip_runtime.h>

// SimpleAttention: B=8, S=2048, H=256
// R4: attn staging via __builtin_amdgcn_global_load_lds (no staging VGPRs ->
//     no scratch spill at 3 blocks/CU), XCD-batch-affine grid (b,q,split),
//     mask prefetched one tile ahead. Rest unchanged from R3.

#define B_ 8
#define S_ 2048
#define H_ 256

typedef __attribute__((ext_vector_type(8))) short s16x8;   // 8 bf16 MFMA A/B frag
typedef __attribute__((ext_vector_type(4))) float f32x4;   // MFMA C/D frag
typedef __attribute__((ext_vector_type(4))) unsigned short u16x4;
typedef __attribute__((ext_vector_type(8))) unsigned short u16x8;

#if __has_builtin(__builtin_amdgcn_exp2f)
#define EXP2F(x) __builtin_amdgcn_exp2f(x)
#else
#define EXP2F(x) exp2f(x)
#endif
#define L2E 1.4426950408889634f

__device__ __forceinline__ unsigned short f2bf(float f) {
  unsigned int u = __builtin_bit_cast(unsigned int, f);
  u += 0x7fffu + ((u >> 16) & 1u);   // RNE
  return (unsigned short)(u >> 16);
}
__device__ __forceinline__ float bf2f(unsigned short h) {
  unsigned int u = ((unsigned int)h) << 16;
  return __builtin_bit_cast(float, u);
}
__device__ __forceinline__ f32x4 mfma_bf16(s16x8 a, s16x8 b, f32x4 c) {
  return __builtin_amdgcn_mfma_f32_16x16x32_bf16(a, b, c, 0, 0, 0);
}
__device__ __forceinline__ float sel4(const float v[4], int r) {
  float t0 = (r & 1) ? v[1] : v[0];
  float t1 = (r & 1) ? v[3] : v[2];
  return (r & 2) ? t1 : t0;
}
// async global->LDS, 16B per lane; LDS dest = uniform base + lane*16
__device__ __forceinline__ void async16(const unsigned short* g, unsigned short* l) {
  __builtin_amdgcn_global_load_lds(
      (const __attribute__((address_space(1))) unsigned int*)g,
      (__attribute__((address_space(3))) unsigned int*)l, 16, 0, 0);
}

// ---------------------------------------------------------------------------
// Kernel 0: W[h][n] fp32 -> Wt[n][h] bf16, LDS-tiled transpose. grid (16,3).
// ---------------------------------------------------------------------------
__global__ __launch_bounds__(256) void wt_kernel(const float* __restrict__ Wq,
                                                 const float* __restrict__ Wk,
                                                 const float* __restrict__ Wv,
                                                 unsigned short* __restrict__ Wt) {
  __shared__ unsigned short tile[64 * 72];
  int z = blockIdx.y;
  const float* W = (z == 0) ? Wq : (z == 1) ? Wk : Wv;
  int n0 = (blockIdx.x & 3) * 64, h0 = (blockIdx.x >> 2) * 64;
  int t = threadIdx.x;
#pragma unroll
  for (int j = 0; j < 4; ++j) {
    int c = j * 256 + t;
    int i = c >> 4, ch = c & 15;
    float4 f = *(const float4*)&W[(h0 + i) * 256 + n0 + ch * 4];
    u16x4 p;
    p[0] = f2bf(f.x); p[1] = f2bf(f.y); p[2] = f2bf(f.z); p[3] = f2bf(f.w);
    *(u16x4*)&tile[i * 72 + ch * 4] = p;
  }
  __syncthreads();
#pragma unroll
  for (int j = 0; j < 2; ++j) {
    int c = j * 256 + t;
    int nr = c >> 3, ch = c & 7;
    u16x8 o;
#pragma unroll
    for (int k = 0; k < 8; ++k) o[k] = tile[(ch * 8 + k) * 72 + nr];
    *(u16x8*)&Wt[z * 65536 + (n0 + nr) * 256 + h0 + ch * 8] = o;
  }
}

// ---------------------------------------------------------------------------
// Kernel 1: projections. Block = 64 rows x 256 cols, 4 waves. grid (256,3).
// ---------------------------------------------------------------------------
__global__ __launch_bounds__(256) void proj_kernel(
    const float* __restrict__ Xq, const float* __restrict__ Xk, const float* __restrict__ Xv,
    const unsigned short* __restrict__ Wt,
    unsigned short* __restrict__ Qb, unsigned short* __restrict__ Kb,
    unsigned short* __restrict__ Vr) {
  __shared__ unsigned short Xs[64 * 32];
  __shared__ unsigned short Ws[256 * 32];

  int z = blockIdx.y;
  const float* X = (z == 0) ? Xq : (z == 1) ? Xk : Xv;
  const unsigned short* Wz = Wt + z * 65536;

  int t = threadIdx.x;
  int w = t >> 6, lane = t & 63, quad = lane >> 4, l15 = lane & 15;
  int m0 = blockIdx.x * 64;

  f32x4 zero4 = {0.f, 0.f, 0.f, 0.f};
  f32x4 acc[16];
#pragma unroll
  for (int i = 0; i < 16; ++i) acc[i] = zero4;

  for (int c8 = 0; c8 < 8; ++c8) {
    {
      int m = t >> 2, p = t & 3;
      const float* src = X + (size_t)(m0 + m) * H_ + c8 * 32 + p * 8;
      float4 f0 = *(const float4*)(src);
      float4 f1 = *(const float4*)(src + 4);
      s16x8 hv;
      hv[0] = (short)f2bf(f0.x); hv[1] = (short)f2bf(f0.y);
      hv[2] = (short)f2bf(f0.z); hv[3] = (short)f2bf(f0.w);
      hv[4] = (short)f2bf(f1.x); hv[5] = (short)f2bf(f1.y);
      hv[6] = (short)f2bf(f1.z); hv[7] = (short)f2bf(f1.w);
      *(s16x8*)&Xs[m * 32 + ((p ^ ((m >> 1) & 3)) << 3)] = hv;
    }
#pragma unroll
    for (int i = 0; i < 4; ++i) {
      int c = i * 256 + t;
      int n = c >> 2, p = c & 3;
      const unsigned short* src = Wz + n * 256 + c8 * 32 + ((p ^ ((n >> 1) & 3)) << 3);
      uint4 dv = *(const uint4*)src;
      *(uint4*)&Ws[n * 32 + (p << 3)] = dv;
    }
    __syncthreads();

    int mloc = w * 16 + l15;
    s16x8 af = *(const s16x8*)&Xs[mloc * 32 + ((quad ^ ((mloc >> 1) & 3)) << 3)];
#pragma unroll
    for (int nf = 0; nf < 16; ++nf) {
      int n = nf * 16 + l15;
      s16x8 bf = *(const s16x8*)&Ws[n * 32 + ((quad ^ ((n >> 1) & 3)) << 3)];
      acc[nf] = mfma_bf16(af, bf, acc[nf]);
    }
    __syncthreads();
  }

  unsigned short* Y = (z == 0) ? Qb : (z == 1) ? Kb : Vr;
  float scale = (z == 0) ? 0.0625f : 1.0f;
#pragma unroll
  for (int nf = 0; nf < 16; ++nf) {
    int n = nf * 16 + l15;
#pragma unroll
    for (int r = 0; r < 4; ++r) {
      int m = m0 + w * 16 + quad * 4 + r;
      Y[(size_t)m * H_ + n] = f2bf(acc[nf][r] * scale);
    }
  }
}

// ---------------------------------------------------------------------------
// Kernel 2: Vr[b][s][d] -> Vt[b][d][s], 64x64 LDS tiles. grid (128, 8).
// ---------------------------------------------------------------------------
__global__ __launch_bounds__(256) void vtrans_kernel(
    const unsigned short* __restrict__ Vr, unsigned short* __restrict__ Vt) {
  __shared__ unsigned short tile[64 * 72];
  int s0 = (blockIdx.x & 31) * 64;
  int d0 = (blockIdx.x >> 5) * 64;
  int b = blockIdx.y;
  int t = threadIdx.x;
#pragma unroll
  for (int j = 0; j < 2; ++j) {
    int c = j * 256 + t;
    int i = c >> 3, ch = c & 7;
    u16x8 v = *(const u16x8*)&Vr[((size_t)b * S_ + s0 + i) * H_ + d0 + ch * 8];
    *(u16x8*)&tile[i * 72 + ch * 8] = v;
  }
  __syncthreads();
#pragma unroll
  for (int j = 0; j < 2; ++j) {
    int c = j * 256 + t;
    int dr = c >> 3, ch = c & 7;
    u16x8 o;
#pragma unroll
    for (int k = 0; k < 8; ++k) o[k] = tile[(ch * 8 + k) * 72 + dr];
    *(u16x8*)&Vt[((size_t)b * H_ + d0 + dr) * S_ + s0 + ch * 8] = o;
  }
}

// ---------------------------------------------------------------------------
// Kernel 3: flash attention, K-split. grid (B=8, S/64=32, nsplit), 4 waves.
// BK=32. LDS: Ks[32][256] 16KB | Vs[256][32] 16KB | Ps[4][16][32] 4KB = 36KB.
// Staging via global_load_lds (async, zero staging VGPRs). blockIdx.x = batch
// so linear_id%8 == batch -> one batch per XCD L2.
// ---------------------------------------------------------------------------
__global__ __launch_bounds__(256, 3) void attn_kernel(
    const unsigned short* __restrict__ Qb, const unsigned short* __restrict__ Kb,
    const unsigned short* __restrict__ Vt, const int* __restrict__ mask,
    unsigned short* __restrict__ Op, float* __restrict__ Ml,
    float* __restrict__ out) {
  __shared__ unsigned short lds[18432];
  unsigned short* Ks = lds;            // [32 key][256 d]
  unsigned short* Vs = lds + 8192;     // [256 d][32 key]
  unsigned short* Ps = lds + 16384;    // [wave][16 q][32 key]

  int t = threadIdx.x;
  int w = t >> 6, lane = t & 63, quad = lane >> 4, l15 = lane & 15;
  int b = blockIdx.x;                  // batch -> XCD affinity
  int q0 = blockIdx.y * 64;
  int split = blockIdx.z, nsplit = gridDim.z;
  int kbeg = (64 * split) / nsplit, kend = (64 * (split + 1)) / nsplit;

  // Q A-frags
  s16x8 qa[8];
  {
    const unsigned short* qp =
        Qb + ((size_t)b * S_ + q0 + w * 16 + l15) * H_ + quad * 8;
#pragma unroll
    for (int c = 0; c < 8; ++c) qa[c] = *(const s16x8*)(qp + 32 * c);
  }

  const unsigned short* Kbb = Kb + (size_t)b * S_ * H_;
  const unsigned short* Vbb = Vt + (size_t)b * H_ * S_;

  // async staging lane roles
  int krow = lane >> 5, kchunk = lane & 31;   // K: 2 key-rows/instr, 32 chunks
  int vrow = lane >> 2, vchunk = lane & 3;    // V: 16 d-rows/instr, 4 chunks

  f32x4 zero4 = {0.f, 0.f, 0.f, 0.f};
  f32x4 acc[16];
#pragma unroll
  for (int i = 0; i < 16; ++i) acc[i] = zero4;
  float m_r[4], l_r[4];
#pragma unroll
  for (int r = 0; r < 4; ++r) { m_r[r] = -1e30f; l_r[r] = 0.f; }

  const int* mbase =
      mask + ((size_t)b * S_ + q0 + w * 16 + quad * 4) * S_ + l15;

  // mask for first tile
  int mv[2][4];
  {
    const int* mr = mbase + kbeg * 32;
#pragma unroll
    for (int nf = 0; nf < 2; ++nf)
#pragma unroll
      for (int r = 0; r < 4; ++r) mv[nf][r] = mr[(size_t)r * S_ + nf * 16];
  }

  for (int kt = kbeg; kt < kend; ++kt) {
    int k0 = kt * 32;
    __syncthreads();   // A: previous tiles consumed
    // ---- async stage K tile: wave w instr j -> key rows 2(w*4+j)+{0,1}
#pragma unroll
    for (int j = 0; j < 4; ++j) {
      int key = (w * 4 + j) * 2 + krow;
      const unsigned short* g =
          Kbb + ((size_t)(k0 + key) << 8) + ((kchunk ^ (key & 7)) << 3);
      async16(g, Ks + (w * 4 + j) * 512);
    }
    // ---- async stage V tile: wave w instr j -> d rows w*64+j*16 .. +15
#pragma unroll
    for (int j = 0; j < 4; ++j) {
      int d = w * 64 + j * 16 + vrow;
      const unsigned short* g =
          Vbb + ((size_t)d << 11) + k0 + ((vchunk ^ (d & 3)) << 3);
      async16(g, Vs + (w * 64 + j * 16) * 32);
    }
    __syncthreads();   // B: vmcnt drained -> tiles visible

    // prefetch mask for next tile (latency hidden under compute)
    int mvn[2][4];
    {
      int ktn = (kt + 1 < kend) ? kt + 1 : kt;
      const int* mr = mbase + ktn * 32;
#pragma unroll
      for (int nf = 0; nf < 2; ++nf)
#pragma unroll
        for (int r = 0; r < 4; ++r) mvn[nf][r] = mr[(size_t)r * S_ + nf * 16];
    }

    // ---- S = Q K^T
    f32x4 sacc[2];
#pragma unroll
    for (int nf = 0; nf < 2; ++nf) sacc[nf] = zero4;
#pragma unroll
    for (int c = 0; c < 8; ++c) {
#pragma unroll
      for (int nf = 0; nf < 2; ++nf) {
        int n = nf * 16 + l15;
        s16x8 kb = *(const s16x8*)&Ks[n * 256 + (((quad + 4 * c) ^ (n & 7)) << 3)];
        sacc[nf] = mfma_bf16(qa[c], kb, sacc[nf]);
      }
    }

    // ---- mask + online softmax
    float pv2[2][4], mt[4];
#pragma unroll
    for (int r = 0; r < 4; ++r) mt[r] = -1e30f;
#pragma unroll
    for (int nf = 0; nf < 2; ++nf)
#pragma unroll
      for (int r = 0; r < 4; ++r) {
        float s = mv[nf][r] ? -1e30f : sacc[nf][r];
        pv2[nf][r] = s;
        mt[r] = fmaxf(mt[r], s);
      }
#pragma unroll
    for (int r = 0; r < 4; ++r) {
      float m = mt[r];
#pragma unroll
      for (int d = 1; d < 16; d <<= 1) m = fmaxf(m, __shfl_xor(m, d, 64));
      mt[r] = m;
    }
    float alpha[4];
#pragma unroll
    for (int r = 0; r < 4; ++r) {
      float mn = fmaxf(m_r[r], mt[r]);
      alpha[r] = EXP2F((m_r[r] - mn) * L2E);
      m_r[r] = mn;
      float rs = 0.f;
#pragma unroll
      for (int nf = 0; nf < 2; ++nf) {
        float p = EXP2F((pv2[nf][r] - mn) * L2E);
        pv2[nf][r] = p;
        rs += p;
      }
#pragma unroll
      for (int d = 1; d < 16; d <<= 1) rs += __shfl_xor(rs, d, 64);
      l_r[r] = l_r[r] * alpha[r] + rs;
    }

    // ---- P -> LDS (wave-private)
#pragma unroll
    for (int nf = 0; nf < 2; ++nf)
#pragma unroll
      for (int r = 0; r < 4; ++r) {
        int key = nf * 16 + l15;
        int ql = quad * 4 + r;
        Ps[w * 512 + ql * 32 + (((key >> 3) ^ (ql & 3)) << 3) + (key & 7)] =
            f2bf(pv2[nf][r]);
      }

    // ---- rescale O^T columns by alpha of q = l15
    {
      float a4[4];
      int srcl = (l15 >> 2) << 4;
#pragma unroll
      for (int r = 0; r < 4; ++r) a4[r] = __shfl(alpha[r], srcl, 64);
      float aq = sel4(a4, l15 & 3);
#pragma unroll
      for (int mf = 0; mf < 16; ++mf) {
        acc[mf][0] *= aq; acc[mf][1] *= aq; acc[mf][2] *= aq; acc[mf][3] *= aq;
      }
    }

    // ---- O^T += V^T P^T
    {
      s16x8 bp = *(const s16x8*)&Ps[w * 512 + l15 * 32 + ((quad ^ (l15 & 3)) << 3)];
#pragma unroll
      for (int mf = 0; mf < 16; ++mf) {
        int d = mf * 16 + l15;
        s16x8 av = *(const s16x8*)&Vs[d * 32 + ((quad ^ (d & 3)) << 3)];
        acc[mf] = mfma_bf16(av, bp, acc[mf]);
      }
    }

    // rotate mask prefetch
#pragma unroll
    for (int nf = 0; nf < 2; ++nf)
#pragma unroll
      for (int r = 0; r < 4; ++r) mv[nf][r] = mvn[nf][r];
  }

  if (gridDim.z == 1) {
    float l4[4];
    int srcl = (l15 >> 2) << 4;
#pragma unroll
    for (int r = 0; r < 4; ++r) l4[r] = __shfl(l_r[r], srcl, 64);
    float lq = sel4(l4, l15 & 3);
    float linv = (lq > 0.f) ? (1.0f / lq) : 0.f;
    float* op = out + ((size_t)b * S_ + q0 + w * 16 + l15) * H_ + quad * 4;
#pragma unroll
    for (int mf = 0; mf < 16; ++mf) {
      float4 o;
      o.x = acc[mf][0] * linv; o.y = acc[mf][1] * linv;
      o.z = acc[mf][2] * linv; o.w = acc[mf][3] * linv;
      *(float4*)(op + mf * 16) = o;
    }
  } else {
    int qg = q0 + w * 16 + l15;
    unsigned short* op =
        Op + (((size_t)split * B_ + b) * S_ + qg) * H_ + quad * 4;
#pragma unroll
    for (int mf = 0; mf < 16; ++mf) {
      u16x4 pk;
      pk[0] = f2bf(acc[mf][0]); pk[1] = f2bf(acc[mf][1]);
      pk[2] = f2bf(acc[mf][2]); pk[3] = f2bf(acc[mf][3]);
      *(u16x4*)(op + mf * 16) = pk;
    }
    if (l15 == 0) {
#pragma unroll
      for (int r = 0; r < 4; ++r) {
        int qr = q0 + w * 16 + quad * 4 + r;
        float2 ml2 = make_float2(m_r[r], l_r[r]);
        *(float2*)&Ml[(((size_t)split * B_ + b) * S_ + qr) * 2] = ml2;
      }
    }
  }
}

// ---------------------------------------------------------------------------
// Kernel 4: combine K-split partials. grid (2048, 8) x 256.
// ---------------------------------------------------------------------------
__global__ __launch_bounds__(256) void combine_kernel(
    const unsigned short* __restrict__ Op, const float* __restrict__ Ml,
    float* __restrict__ out, int nsplit) {
  int q = blockIdx.x, b = blockIdx.y, d = threadIdx.x;
  float M = -1e30f;
  for (int i = 0; i < nsplit; ++i)
    M = fmaxf(M, Ml[(((size_t)i * B_ + b) * S_ + q) * 2]);
  float osum = 0.f, lsum = 0.f;
  for (int i = 0; i < nsplit; ++i) {
    size_t ro = ((size_t)i * B_ + b) * S_ + q;
    float mi = Ml[ro * 2], li = Ml[ro * 2 + 1];
    float wgt = EXP2F((mi - M) * L2E);
    lsum += wgt * li;
    osum += wgt * bf2f(Op[ro * H_ + d]);
  }
  float linv = (lsum > 0.f) ? (1.0f / lsum) : 0.f;
  out[((size_t)b * S_ + q) * H_ + d] = osum * linv;
}

// ---------------------------------------------------------------------------
extern "C" void kernel_launch(void* const* d_in, const int* in_sizes, int n_in,
                              void* d_out, int out_size, void* d_ws, size_t ws_size,
                              hipStream_t stream) {
  const float* k_in = (const float*)d_in[0];
  const float* q_in = (const float*)d_in[1];
  const float* v_in = (const float*)d_in[2];
  const int* mask = (const int*)d_in[3];
  const float* Wq = (const float*)d_in[4];
  const float* Wk = (const float*)d_in[5];
  const float* Wv = (const float*)d_in[6];
  float* out = (float*)d_out;

  unsigned short* Qb = (unsigned short*)d_ws;
  unsigned short* Kb = Qb + (size_t)4194304;
  unsigned short* Vr = Kb + (size_t)4194304;
  unsigned short* Vt = Vr + (size_t)4194304;
  unsigned short* Wt = Vt + (size_t)4194304;
  unsigned short* Op = Wt + (size_t)196608;
  float* Ml = (float*)(Op + (size_t)12582912);
  const size_t need = 59506688;
  int nsplit = (ws_size >= need) ? 3 : 1;

  hipLaunchKernelGGL(wt_kernel, dim3(16, 3), dim3(256), 0, stream, Wq, Wk, Wv, Wt);
  hipLaunchKernelGGL(proj_kernel, dim3(256, 3), dim3(256), 0, stream,
                     q_in, k_in, v_in, Wt, Qb, Kb, Vr);
  hipLaunchKernelGGL(vtrans_kernel, dim3(128, 8), dim3(256), 0, stream, Vr, Vt);
  hipLaunchKernelGGL(attn_kernel, dim3(8, 32, nsplit), dim3(256), 0, stream,
                     Qb, Kb, Vt, mask, Op, Ml, out);
  if (nsplit > 1)
    hipLaunchKernelGGL(combine_kernel, dim3(2048, 8), dim3(256), 0, stream,
                       Op, Ml, out, nsplit);
}